// Round 6
// baseline (600.902 us; speedup 1.0000x reference)
//
#include <hip/hip_runtime.h>
#include <math.h>

#define H 128
#define RBITS 13
#define RSIZE 8192        // nodes per range (32 KB packed LDS histogram)
#define NCHUNK 96         // edge chunks

__device__ inline unsigned short f2bf(float f) {      // RNE float->bf16
  unsigned u = __float_as_uint(f);
  return (unsigned short)((u + 0x7FFF + ((u >> 16) & 1)) >> 16);
}

// ---------------- histogram: packed src|dst counts, per-(range,chunk), LDS atomics only ----------------
__global__ __launch_bounds__(256) void k_hist(const int* __restrict__ src,
                                              const int* __restrict__ dst,
                                              int* __restrict__ ppack, int E) {
  int r = blockIdx.x / NCHUNK, c = blockIdx.x % NCHUNK;
  int base = r << RBITS;
  __shared__ int h[RSIZE];                 // low16 = src count, high16 = dst count
  for (int i = threadIdx.x; i < RSIZE; i += 256) h[i] = 0;
  __syncthreads();
  int e0 = (int)(((long long)E * c) / NCHUNK);
  int e1 = (int)(((long long)E * (c + 1)) / NCHUNK);
  for (int e = e0 + threadIdx.x; e < e1; e += 256) {
    unsigned ls = (unsigned)(src[e] - base);
    if (ls < RSIZE) atomicAdd(&h[ls], 1);
    unsigned ld = (unsigned)(dst[e] - base);
    if (ld < RSIZE) atomicAdd(&h[ld], 0x10000);
  }
  __syncthreads();
  int* p = ppack + (((size_t)(r * NCHUNK + c)) << RBITS);
  for (int i = threadIdx.x; i < RSIZE; i += 256) p[i] = h[i];
}

// ---------------- reduce: unpack counts -> degrees/norms; rewrite ppack as dst chunk-prefix ----------------
__global__ void k_reduce(int* __restrict__ ppack,
                         int* __restrict__ ind, float* __restrict__ onorm,
                         float* __restrict__ inorm, int N) {
  int i = blockIdx.x * blockDim.x + threadIdx.x;
  if (i >= N) return;
  int r = i >> RBITS, l = i & (RSIZE - 1);
  size_t rb = ((size_t)r * NCHUNK) << RBITS;
  int sumS = 0, run = 0;
  for (int c = 0; c < NCHUNK; ++c) {
    size_t idx = rb + ((size_t)c << RBITS) + l;
    int v = ppack[idx];
    sumS += v & 0xFFFF;
    ppack[idx] = run;           // exclusive dst prefix over chunks
    run += (v >> 16) & 0xFFFF;
  }
  ind[i] = run;
  int od = sumS < 1 ? 1 : sumS;
  int id = run < 1 ? 1 : run;
  onorm[i] = rsqrtf((float)od);
  inorm[i] = rsqrtf((float)id);
}

// ---------------- CSR row_ptr: three-phase multi-block exclusive scan ----------------
__global__ __launch_bounds__(1024) void k_scan_blocks(const int* __restrict__ counts,
                                                      int* __restrict__ row_ptr,
                                                      int* __restrict__ blk_sums, int N) {
  __shared__ int buf[1024];
  int i = blockIdx.x * 1024 + threadIdx.x;
  int v = (i < N) ? counts[i] : 0;
  buf[threadIdx.x] = v;
  __syncthreads();
#pragma unroll
  for (int off = 1; off < 1024; off <<= 1) {
    int t = 0;
    if (threadIdx.x >= off) t = buf[threadIdx.x - off];
    __syncthreads();
    if (threadIdx.x >= off) buf[threadIdx.x] += t;
    __syncthreads();
  }
  if (i < N) row_ptr[i] = buf[threadIdx.x] - v;  // local exclusive
  if (threadIdx.x == 1023) blk_sums[blockIdx.x] = buf[1023];
}

__global__ __launch_bounds__(1024) void k_scan_tops(int* __restrict__ blk_sums,
                                                    int* __restrict__ blk_offs,
                                                    int* __restrict__ row_ptr,
                                                    int nb, int N) {
  __shared__ int buf[1024];
  int v = (threadIdx.x < nb) ? blk_sums[threadIdx.x] : 0;
  buf[threadIdx.x] = v;
  __syncthreads();
#pragma unroll
  for (int off = 1; off < 1024; off <<= 1) {
    int t = 0;
    if (threadIdx.x >= off) t = buf[threadIdx.x - off];
    __syncthreads();
    if (threadIdx.x >= off) buf[threadIdx.x] += t;
    __syncthreads();
  }
  if (threadIdx.x < nb) blk_offs[threadIdx.x] = buf[threadIdx.x] - v;
  if (threadIdx.x == 1023) row_ptr[N] = buf[1023];
}

__global__ void k_scan_add(int* __restrict__ row_ptr, const int* __restrict__ blk_offs, int N) {
  int i = blockIdx.x * blockDim.x + threadIdx.x;
  if (i < N) row_ptr[i] += blk_offs[i >> 10];
}

// ---------------- CSR fill: LDS cursors seeded from row_ptr + chunk prefix ----------------
__global__ __launch_bounds__(256) void k_fill_nr(const int* __restrict__ src,
                                                 const int* __restrict__ dst,
                                                 const int* __restrict__ row_ptr,
                                                 const int* __restrict__ ppfx,
                                                 int* __restrict__ csr, int N, int E) {
  int r = blockIdx.x / NCHUNK, c = blockIdx.x % NCHUNK;
  int base = r << RBITS;
  __shared__ int cur[RSIZE];
  const int* pd = ppfx + (((size_t)(r * NCHUNK + c)) << RBITS);
  for (int i = threadIdx.x; i < RSIZE; i += 256) {
    int node = base + i;
    cur[i] = (node < N) ? (row_ptr[node] + pd[i]) : 0;
  }
  __syncthreads();
  int e0 = (int)(((long long)E * c) / NCHUNK);
  int e1 = (int)(((long long)E * (c + 1)) / NCHUNK);
  for (int e = e0 + threadIdx.x; e < e1; e += 256) {
    unsigned ld = (unsigned)(dst[e] - base);
    if (ld < RSIZE) {
      int pos = atomicAdd(&cur[ld], 1);   // LDS atomic
      csr[pos] = src[e];
    }
  }
}

// ---------------- fp32 GEMM, 64x128 tile, 8x8 per thread (128 threads) ----------------
// out = act(A[NxK] @ W[Kx128] + b); epilogue either fp32 (optional silu) or
// bf16 with silu + onorm fold. In-place safe for fp32 path (block reads only own rows).
__global__ __launch_bounds__(128) void k_gemm2(const float* __restrict__ A,
                                               const float* __restrict__ W,
                                               const float* __restrict__ bias,
                                               const float* __restrict__ onorm,
                                               float* __restrict__ out_f,
                                               unsigned short* __restrict__ out_bf,
                                               int N, int K, int do_silu) {
  __shared__ float Ws[32][132];   // padded
  __shared__ float AsT[32][68];   // padded
  const int t = threadIdx.x;
  const int cg = t & 15;          // cols cg*8 .. +7
  const int rg = t >> 4;          // rows rg*8 .. +7
  const int r0 = blockIdx.x * 64;
  float acc[8][8] = {};
  const bool k4 = (K & 3) == 0;
  for (int k0 = 0; k0 < K; k0 += 32) {
    // W tile 32x128 (1024 float4, 8 per thread)
#pragma unroll
    for (int p = 0; p < 8; ++p) {
      int idx4 = t + p * 128;
      int kk = idx4 >> 5;
      int cc = (idx4 & 31) * 4;
      float4 w = make_float4(0.f, 0.f, 0.f, 0.f);
      if (k0 + kk < K) w = *(const float4*)(W + (size_t)(k0 + kk) * H + cc);
      *(float4*)(&Ws[kk][cc]) = w;
    }
    // A tile 64 rows x 32 k, transposed
    if (k4) {
#pragma unroll
      for (int p = 0; p < 4; ++p) {
        int idx4 = t + p * 128;         // 0..511
        int r = idx4 >> 3;              // 0..63
        int kk4 = (idx4 & 7) * 4;
        int row = r0 + r;
        float4 a = make_float4(0.f, 0.f, 0.f, 0.f);
        if (row < N && k0 + kk4 < K) a = *(const float4*)(A + (size_t)row * K + k0 + kk4);
        AsT[kk4 + 0][r] = a.x; AsT[kk4 + 1][r] = a.y;
        AsT[kk4 + 2][r] = a.z; AsT[kk4 + 3][r] = a.w;
      }
    } else {
#pragma unroll
      for (int p = 0; p < 16; ++p) {
        int idx = t + p * 128;          // 0..2047
        int r = idx >> 5;
        int kk = idx & 31;
        int row = r0 + r;
        float a = 0.f;
        if (row < N && k0 + kk < K) a = A[(size_t)row * K + k0 + kk];
        AsT[kk][r] = a;
      }
    }
    __syncthreads();
#pragma unroll
    for (int kk = 0; kk < 32; ++kk) {
      float a_[8], w_[8];
      *(float4*)&a_[0] = *(const float4*)(&AsT[kk][rg * 8]);
      *(float4*)&a_[4] = *(const float4*)(&AsT[kk][rg * 8 + 4]);
      *(float4*)&w_[0] = *(const float4*)(&Ws[kk][cg * 8]);
      *(float4*)&w_[4] = *(const float4*)(&Ws[kk][cg * 8 + 4]);
#pragma unroll
      for (int ri = 0; ri < 8; ++ri)
#pragma unroll
        for (int ci = 0; ci < 8; ++ci)
          acc[ri][ci] += a_[ri] * w_[ci];
    }
    __syncthreads();
  }
  float bv[8];
  *(float4*)&bv[0] = *(const float4*)(bias + cg * 8);
  *(float4*)&bv[4] = *(const float4*)(bias + cg * 8 + 4);
  if (out_bf) {
#pragma unroll
    for (int ri = 0; ri < 8; ++ri) {
      int row = r0 + rg * 8 + ri;
      if (row < N) {
        float on = onorm[row];
        unsigned short u[8];
#pragma unroll
        for (int ci = 0; ci < 8; ++ci) {
          float v = acc[ri][ci] + bv[ci];
          v = v / (1.f + expf(-v));     // silu
          u[ci] = f2bf(v * on);
        }
        uint4 pk;
        pk.x = (unsigned)u[0] | ((unsigned)u[1] << 16);
        pk.y = (unsigned)u[2] | ((unsigned)u[3] << 16);
        pk.z = (unsigned)u[4] | ((unsigned)u[5] << 16);
        pk.w = (unsigned)u[6] | ((unsigned)u[7] << 16);
        *(uint4*)(out_bf + (size_t)row * H + cg * 8) = pk;
      }
    }
  } else {
#pragma unroll
    for (int ri = 0; ri < 8; ++ri) {
      int row = r0 + rg * 8 + ri;
      if (row < N) {
        float o[8];
#pragma unroll
        for (int ci = 0; ci < 8; ++ci) {
          float v = acc[ri][ci] + bv[ci];
          if (do_silu) v = v / (1.f + expf(-v));
          o[ci] = v;
        }
        *(float4*)(out_f + (size_t)row * H + cg * 8)     = *(float4*)&o[0];
        *(float4*)(out_f + (size_t)row * H + cg * 8 + 4) = *(float4*)&o[4];
      }
    }
  }
}

// ---------------- gather (bf16 rows, onorm pre-folded): agg[v] = inorm[v]*sum h[src] ----------------
__global__ __launch_bounds__(64) void k_gather_bf(const unsigned* __restrict__ hb, // N x 64 words
                                                  const int* __restrict__ csr_src,
                                                  const int* __restrict__ row_ptr,
                                                  const float* __restrict__ inorm,
                                                  float* __restrict__ agg, int N) {
  int v = blockIdx.x;
  int t = threadIdx.x;
  int b = row_ptr[v], e = row_ptr[v + 1];
  float ax = 0.f, ay = 0.f;
  for (int i = b; i < e; ++i) {
    int s = csr_src[i];
    unsigned p = hb[(size_t)s * 64 + t];
    ax += __uint_as_float(p << 16);           // col 2t
    ay += __uint_as_float(p & 0xFFFF0000u);   // col 2t+1
  }
  float inn = inorm[v];
  *(float2*)(agg + (size_t)v * H + t * 2) = make_float2(ax * inn, ay * inn);
}

// ---------------- pooling: segment-sum over sorted graph_ids ----------------
__global__ __launch_bounds__(128) void k_pool(const float* __restrict__ h,
                                              const int* __restrict__ gid,
                                              float* pooled, int N) {
  int c = threadIdx.x;
  int v0 = blockIdx.x * 128;
  int vend = v0 + 128; if (vend > N) vend = N;
  if (v0 >= N) return;
  int cur = gid[v0];
  float acc = 0.f;
  for (int v = v0; v < vend; ++v) {
    int g = gid[v];
    if (g != cur) {
      atomicAdd(&pooled[(size_t)cur * H + c], acc);
      acc = 0.f; cur = g;
    }
    acc += h[(size_t)v * H + c];
  }
  atomicAdd(&pooled[(size_t)cur * H + c], acc);
}

// ---------------- final ff ----------------
__global__ __launch_bounds__(128) void k_ff(const float* __restrict__ pooled,
                                            const float* __restrict__ Wff,
                                            const float* __restrict__ bff,
                                            float* __restrict__ out, int G) {
  int g = blockIdx.x;
  int t = threadIdx.x;
  float v = pooled[(size_t)g * H + t] * Wff[t];
#pragma unroll
  for (int off = 32; off > 0; off >>= 1) v += __shfl_down(v, off, 64);
  __shared__ float red[2];
  if ((t & 63) == 0) red[t >> 6] = v;
  __syncthreads();
  if (t == 0) out[g] = red[0] + red[1] + bff[0];
}

extern "C" void kernel_launch(void* const* d_in, const int* in_sizes, int n_in,
                              void* d_out, int out_size, void* d_ws, size_t ws_size,
                              hipStream_t stream) {
  const float* x     = (const float*)d_in[0];
  const float* W_in  = (const float*)d_in[1];
  const float* b_in  = (const float*)d_in[2];
  const float* W_g0  = (const float*)d_in[3];
  const float* b_g0  = (const float*)d_in[4];
  const float* W_g1  = (const float*)d_in[5];
  const float* b_g1  = (const float*)d_in[6];
  const float* W_g2  = (const float*)d_in[7];
  const float* b_g2  = (const float*)d_in[8];
  const float* W_out = (const float*)d_in[9];
  const float* b_out = (const float*)d_in[10];
  const float* W_ff  = (const float*)d_in[11];
  const float* b_ff  = (const float*)d_in[12];
  const int* src = (const int*)d_in[13];
  const int* dst = (const int*)d_in[14];
  const int* gid = (const int*)d_in[15];
  float* out = (float*)d_out;

  const int N = in_sizes[15];          // 50000
  const int E = in_sizes[13];          // 600000
  const int K_IN = in_sizes[1] / H;    // 74
  const int G = out_size;              // 500

  char* ws = (char*)d_ws;
  size_t off = 0;
  auto alloc = [&](size_t bytes) -> void* {
    void* p = ws + off;
    off = (off + bytes + 255) & ~(size_t)255;
    return p;
  };
  float*          agg  = (float*)alloc((size_t)N * H * 4);          // fp32 gather out / h3 / hfinal
  unsigned short* hb   = (unsigned short*)alloc((size_t)N * H * 2); // bf16 gather in
  float* onorm   = (float*)alloc((size_t)N * 4);
  float* inorm   = (float*)alloc((size_t)N * 4);
  int*   ind     = (int*)alloc((size_t)N * 4);
  int*   row_ptr = (int*)alloc((size_t)(N + 1) * 4);
  int*   csr     = (int*)alloc((size_t)E * 4);
  float* pooled  = (float*)alloc((size_t)G * H * 4);
  int nb = (N + 1023) / 1024;
  int*   blk_sums = (int*)alloc((size_t)nb * 4);
  int*   blk_offs = (int*)alloc((size_t)nb * 4);

  // packed hist partials alias agg (dead until first gather, long after CSR build):
  // nr*NCHUNK*RSIZE ints = 7*96*8192*4 = 22.0 MB <= N*H*4 = 25.6 MB.
  int nr = (N + RSIZE - 1) / RSIZE;
  int* ppack = (int*)agg;

  hipMemsetAsync(pooled, 0, (size_t)G * H * 4, stream);

  k_hist<<<nr * NCHUNK, 256, 0, stream>>>(src, dst, ppack, E);
  k_reduce<<<(N + 255) / 256, 256, 0, stream>>>(ppack, ind, onorm, inorm, N);
  k_scan_blocks<<<nb, 1024, 0, stream>>>(ind, row_ptr, blk_sums, N);
  k_scan_tops<<<1, 1024, 0, stream>>>(blk_sums, blk_offs, row_ptr, nb, N);
  k_scan_add<<<(N + 255) / 256, 256, 0, stream>>>(row_ptr, blk_offs, N);
  k_fill_nr<<<nr * NCHUNK, 256, 0, stream>>>(src, dst, row_ptr, ppack, csr, N, E);

  int gblk = (N + 63) / 64;
  // embedding_in: hb0 = bf16(silu(x @ W_in + b_in) * onorm)
  k_gemm2<<<gblk, 128, 0, stream>>>(x, W_in, b_in, onorm, nullptr, hb, N, K_IN, 1);

  // layer 0
  k_gather_bf<<<N, 64, 0, stream>>>((const unsigned*)hb, csr, row_ptr, inorm, agg, N);
  k_gemm2<<<gblk, 128, 0, stream>>>(agg, W_g0, b_g0, onorm, nullptr, hb, N, H, 1);
  // layer 1
  k_gather_bf<<<N, 64, 0, stream>>>((const unsigned*)hb, csr, row_ptr, inorm, agg, N);
  k_gemm2<<<gblk, 128, 0, stream>>>(agg, W_g1, b_g1, onorm, nullptr, hb, N, H, 1);
  // layer 2: output feeds GEMM (sequential) -> fp32 in place
  k_gather_bf<<<N, 64, 0, stream>>>((const unsigned*)hb, csr, row_ptr, inorm, agg, N);
  k_gemm2<<<gblk, 128, 0, stream>>>(agg, W_g2, b_g2, nullptr, agg, nullptr, N, H, 1);

  // embedding_out (no act), in-place
  k_gemm2<<<gblk, 128, 0, stream>>>(agg, W_out, b_out, nullptr, agg, nullptr, N, H, 0);

  k_pool<<<(N + 127) / 128, 128, 0, stream>>>(agg, gid, pooled, N);
  k_ff<<<G, 128, 0, stream>>>(pooled, W_ff, b_ff, out, G);
}

// Round 7
// 479.981 us; speedup vs baseline: 1.2519x; 1.2519x over previous
//
#include <hip/hip_runtime.h>
#include <math.h>

#define H 128
#define RBITS 13
#define RSIZE 8192        // nodes per range (32 KB packed LDS histogram)
#define NCHUNK 96         // edge chunks

__device__ inline unsigned short f2bf(float f) {      // RNE float->bf16
  unsigned u = __float_as_uint(f);
  return (unsigned short)((u + 0x7FFF + ((u >> 16) & 1)) >> 16);
}

// ---------------- histogram: packed src|dst counts, per-(range,chunk), LDS atomics only ----------------
__global__ __launch_bounds__(256) void k_hist(const int* __restrict__ src,
                                              const int* __restrict__ dst,
                                              int* __restrict__ ppack, int E) {
  int r = blockIdx.x / NCHUNK, c = blockIdx.x % NCHUNK;
  int base = r << RBITS;
  __shared__ int h[RSIZE];                 // low16 = src count, high16 = dst count
  for (int i = threadIdx.x; i < RSIZE; i += 256) h[i] = 0;
  __syncthreads();
  int e0 = (int)(((long long)E * c) / NCHUNK);
  int e1 = (int)(((long long)E * (c + 1)) / NCHUNK);
  for (int e = e0 + threadIdx.x; e < e1; e += 256) {
    unsigned ls = (unsigned)(src[e] - base);
    if (ls < RSIZE) atomicAdd(&h[ls], 1);
    unsigned ld = (unsigned)(dst[e] - base);
    if (ld < RSIZE) atomicAdd(&h[ld], 0x10000);
  }
  __syncthreads();
  int* p = ppack + (((size_t)(r * NCHUNK + c)) << RBITS);
  for (int i = threadIdx.x; i < RSIZE; i += 256) p[i] = h[i];
}

// ---------------- reduce: unpack counts -> degrees/norms; rewrite ppack as dst chunk-prefix ----------------
__global__ void k_reduce(int* __restrict__ ppack,
                         int* __restrict__ ind, float* __restrict__ onorm,
                         float* __restrict__ inorm, int N) {
  int i = blockIdx.x * blockDim.x + threadIdx.x;
  if (i >= N) return;
  int r = i >> RBITS, l = i & (RSIZE - 1);
  size_t rb = ((size_t)r * NCHUNK) << RBITS;
  int sumS = 0, run = 0;
  for (int c = 0; c < NCHUNK; ++c) {
    size_t idx = rb + ((size_t)c << RBITS) + l;
    int v = ppack[idx];
    sumS += v & 0xFFFF;
    ppack[idx] = run;           // exclusive dst prefix over chunks
    run += (v >> 16) & 0xFFFF;
  }
  ind[i] = run;
  int od = sumS < 1 ? 1 : sumS;
  int id = run < 1 ? 1 : run;
  onorm[i] = rsqrtf((float)od);
  inorm[i] = rsqrtf((float)id);
}

// ---------------- CSR row_ptr: three-phase multi-block exclusive scan ----------------
__global__ __launch_bounds__(1024) void k_scan_blocks(const int* __restrict__ counts,
                                                      int* __restrict__ row_ptr,
                                                      int* __restrict__ blk_sums, int N) {
  __shared__ int buf[1024];
  int i = blockIdx.x * 1024 + threadIdx.x;
  int v = (i < N) ? counts[i] : 0;
  buf[threadIdx.x] = v;
  __syncthreads();
#pragma unroll
  for (int off = 1; off < 1024; off <<= 1) {
    int t = 0;
    if (threadIdx.x >= off) t = buf[threadIdx.x - off];
    __syncthreads();
    if (threadIdx.x >= off) buf[threadIdx.x] += t;
    __syncthreads();
  }
  if (i < N) row_ptr[i] = buf[threadIdx.x] - v;  // local exclusive
  if (threadIdx.x == 1023) blk_sums[blockIdx.x] = buf[1023];
}

__global__ __launch_bounds__(1024) void k_scan_tops(int* __restrict__ blk_sums,
                                                    int* __restrict__ blk_offs,
                                                    int* __restrict__ row_ptr,
                                                    int nb, int N) {
  __shared__ int buf[1024];
  int v = (threadIdx.x < nb) ? blk_sums[threadIdx.x] : 0;
  buf[threadIdx.x] = v;
  __syncthreads();
#pragma unroll
  for (int off = 1; off < 1024; off <<= 1) {
    int t = 0;
    if (threadIdx.x >= off) t = buf[threadIdx.x - off];
    __syncthreads();
    if (threadIdx.x >= off) buf[threadIdx.x] += t;
    __syncthreads();
  }
  if (threadIdx.x < nb) blk_offs[threadIdx.x] = buf[threadIdx.x] - v;
  if (threadIdx.x == 1023) row_ptr[N] = buf[1023];
}

__global__ void k_scan_add(int* __restrict__ row_ptr, const int* __restrict__ blk_offs, int N) {
  int i = blockIdx.x * blockDim.x + threadIdx.x;
  if (i < N) row_ptr[i] += blk_offs[i >> 10];
}

// ---------------- CSR fill: LDS cursors seeded from row_ptr + chunk prefix ----------------
__global__ __launch_bounds__(256) void k_fill_nr(const int* __restrict__ src,
                                                 const int* __restrict__ dst,
                                                 const int* __restrict__ row_ptr,
                                                 const int* __restrict__ ppfx,
                                                 int* __restrict__ csr, int N, int E) {
  int r = blockIdx.x / NCHUNK, c = blockIdx.x % NCHUNK;
  int base = r << RBITS;
  __shared__ int cur[RSIZE];
  const int* pd = ppfx + (((size_t)(r * NCHUNK + c)) << RBITS);
  for (int i = threadIdx.x; i < RSIZE; i += 256) {
    int node = base + i;
    cur[i] = (node < N) ? (row_ptr[node] + pd[i]) : 0;
  }
  __syncthreads();
  int e0 = (int)(((long long)E * c) / NCHUNK);
  int e1 = (int)(((long long)E * (c + 1)) / NCHUNK);
  for (int e = e0 + threadIdx.x; e < e1; e += 256) {
    unsigned ld = (unsigned)(dst[e] - base);
    if (ld < RSIZE) {
      int pos = atomicAdd(&cur[ld], 1);   // LDS atomic
      csr[pos] = src[e];
    }
  }
}

// ---------------- fp32 GEMM: 32x128 tile, 256 threads, 4x4/thread ----------------
// (proven: conflict-free cg*4 b128 pattern, ~80 VGPR, high occupancy)
// epilogue: out_bf!=null -> bf16(silu(.)*onorm); else fp32 (optional silu).
// In-place safe for fp32 path (block reads only its own 32 rows).
__global__ __launch_bounds__(256) void k_gemm(const float* __restrict__ A,
                                              const float* __restrict__ W,
                                              const float* __restrict__ bias,
                                              const float* __restrict__ onorm,
                                              float* __restrict__ out_f,
                                              unsigned short* __restrict__ out_bf,
                                              int N, int K, int do_silu) {
  __shared__ float Ws[32][H];     // 16 KB
  __shared__ float AsT[32][36];   // padded stride 36 floats
  const int t = threadIdx.x;
  const int cg = t & 31;
  const int rg = t >> 5;
  const int r0 = blockIdx.x * 32;
  float acc[4][4] = {};
  for (int k0 = 0; k0 < K; k0 += 32) {
#pragma unroll
    for (int p = 0; p < 4; ++p) {
      int idx4 = t + p * 256;
      int kk = idx4 >> 5;
      int cc = (idx4 & 31) * 4;
      float4 w = make_float4(0.f, 0.f, 0.f, 0.f);
      if (k0 + kk < K) w = *(const float4*)(W + (size_t)(k0 + kk) * H + cc);
      *(float4*)(&Ws[kk][cc]) = w;
    }
#pragma unroll
    for (int p = 0; p < 4; ++p) {
      int idx = t + p * 256;
      int r = idx >> 5;
      int kk = idx & 31;
      int row = r0 + r;
      float a = 0.f;
      if (row < N && k0 + kk < K) a = A[(size_t)row * K + k0 + kk];
      AsT[kk][r] = a;
    }
    __syncthreads();
#pragma unroll
    for (int kk = 0; kk < 32; ++kk) {
      float4 a4 = *(const float4*)(&AsT[kk][rg * 4]);
      float4 w4 = *(const float4*)(&Ws[kk][cg * 4]);
      float av[4] = {a4.x, a4.y, a4.z, a4.w};
      float wv[4] = {w4.x, w4.y, w4.z, w4.w};
#pragma unroll
      for (int ri = 0; ri < 4; ++ri)
#pragma unroll
        for (int ci = 0; ci < 4; ++ci)
          acc[ri][ci] += av[ri] * wv[ci];
    }
    __syncthreads();
  }
  float4 b4 = *(const float4*)(bias + cg * 4);
  float bv[4] = {b4.x, b4.y, b4.z, b4.w};
  if (out_bf) {
#pragma unroll
    for (int ri = 0; ri < 4; ++ri) {
      int row = r0 + rg * 4 + ri;
      if (row < N) {
        float on = onorm[row];
        unsigned short u[4];
#pragma unroll
        for (int ci = 0; ci < 4; ++ci) {
          float v = acc[ri][ci] + bv[ci];
          v = v / (1.f + expf(-v));     // silu
          u[ci] = f2bf(v * on);
        }
        uint2 pk;
        pk.x = (unsigned)u[0] | ((unsigned)u[1] << 16);
        pk.y = (unsigned)u[2] | ((unsigned)u[3] << 16);
        *(uint2*)(out_bf + (size_t)row * H + cg * 4) = pk;
      }
    }
  } else {
#pragma unroll
    for (int ri = 0; ri < 4; ++ri) {
      int row = r0 + rg * 4 + ri;
      if (row < N) {
        float4 o;
        float* op = (float*)&o;
#pragma unroll
        for (int ci = 0; ci < 4; ++ci) {
          float v = acc[ri][ci] + bv[ci];
          if (do_silu) v = v / (1.f + expf(-v));
          op[ci] = v;
        }
        *(float4*)(out_f + (size_t)row * H + cg * 4) = o;
      }
    }
  }
}

// ---------------- gather (bf16 rows, onorm pre-folded): agg[v] = inorm[v]*sum h[src] ----------------
__global__ __launch_bounds__(64) void k_gather_bf(const unsigned* __restrict__ hb, // N x 64 words
                                                  const int* __restrict__ csr_src,
                                                  const int* __restrict__ row_ptr,
                                                  const float* __restrict__ inorm,
                                                  float* __restrict__ agg, int N) {
  int v = blockIdx.x;
  int t = threadIdx.x;
  int b = row_ptr[v], e = row_ptr[v + 1];
  float ax = 0.f, ay = 0.f;
  for (int i = b; i < e; ++i) {
    int s = csr_src[i];
    unsigned p = hb[(size_t)s * 64 + t];
    ax += __uint_as_float(p << 16);           // col 2t
    ay += __uint_as_float(p & 0xFFFF0000u);   // col 2t+1
  }
  float inn = inorm[v];
  *(float2*)(agg + (size_t)v * H + t * 2) = make_float2(ax * inn, ay * inn);
}

// ---------------- pooling: segment-sum over sorted graph_ids ----------------
__global__ __launch_bounds__(128) void k_pool(const float* __restrict__ h,
                                              const int* __restrict__ gid,
                                              float* pooled, int N) {
  int c = threadIdx.x;
  int v0 = blockIdx.x * 128;
  int vend = v0 + 128; if (vend > N) vend = N;
  if (v0 >= N) return;
  int cur = gid[v0];
  float acc = 0.f;
  for (int v = v0; v < vend; ++v) {
    int g = gid[v];
    if (g != cur) {
      atomicAdd(&pooled[(size_t)cur * H + c], acc);
      acc = 0.f; cur = g;
    }
    acc += h[(size_t)v * H + c];
  }
  atomicAdd(&pooled[(size_t)cur * H + c], acc);
}

// ---------------- final ff ----------------
__global__ __launch_bounds__(128) void k_ff(const float* __restrict__ pooled,
                                            const float* __restrict__ Wff,
                                            const float* __restrict__ bff,
                                            float* __restrict__ out, int G) {
  int g = blockIdx.x;
  int t = threadIdx.x;
  float v = pooled[(size_t)g * H + t] * Wff[t];
#pragma unroll
  for (int off = 32; off > 0; off >>= 1) v += __shfl_down(v, off, 64);
  __shared__ float red[2];
  if ((t & 63) == 0) red[t >> 6] = v;
  __syncthreads();
  if (t == 0) out[g] = red[0] + red[1] + bff[0];
}

extern "C" void kernel_launch(void* const* d_in, const int* in_sizes, int n_in,
                              void* d_out, int out_size, void* d_ws, size_t ws_size,
                              hipStream_t stream) {
  const float* x     = (const float*)d_in[0];
  const float* W_in  = (const float*)d_in[1];
  const float* b_in  = (const float*)d_in[2];
  const float* W_g0  = (const float*)d_in[3];
  const float* b_g0  = (const float*)d_in[4];
  const float* W_g1  = (const float*)d_in[5];
  const float* b_g1  = (const float*)d_in[6];
  const float* W_g2  = (const float*)d_in[7];
  const float* b_g2  = (const float*)d_in[8];
  const float* W_out = (const float*)d_in[9];
  const float* b_out = (const float*)d_in[10];
  const float* W_ff  = (const float*)d_in[11];
  const float* b_ff  = (const float*)d_in[12];
  const int* src = (const int*)d_in[13];
  const int* dst = (const int*)d_in[14];
  const int* gid = (const int*)d_in[15];
  float* out = (float*)d_out;

  const int N = in_sizes[15];          // 50000
  const int E = in_sizes[13];          // 600000
  const int K_IN = in_sizes[1] / H;    // 74
  const int G = out_size;              // 500

  char* ws = (char*)d_ws;
  size_t off = 0;
  auto alloc = [&](size_t bytes) -> void* {
    void* p = ws + off;
    off = (off + bytes + 255) & ~(size_t)255;
    return p;
  };
  float*          agg  = (float*)alloc((size_t)N * H * 4);          // fp32 gather out / h3 / hfinal
  unsigned short* hb   = (unsigned short*)alloc((size_t)N * H * 2); // bf16 gather in
  float* onorm   = (float*)alloc((size_t)N * 4);
  float* inorm   = (float*)alloc((size_t)N * 4);
  int*   ind     = (int*)alloc((size_t)N * 4);
  int*   row_ptr = (int*)alloc((size_t)(N + 1) * 4);
  int*   csr     = (int*)alloc((size_t)E * 4);
  float* pooled  = (float*)alloc((size_t)G * H * 4);
  int nb = (N + 1023) / 1024;
  int*   blk_sums = (int*)alloc((size_t)nb * 4);
  int*   blk_offs = (int*)alloc((size_t)nb * 4);

  // packed hist partials alias agg (dead until first gather, long after CSR build):
  // nr*NCHUNK*RSIZE ints = 7*96*8192*4 = 22.0 MB <= N*H*4 = 25.6 MB.
  int nr = (N + RSIZE - 1) / RSIZE;
  int* ppack = (int*)agg;

  hipMemsetAsync(pooled, 0, (size_t)G * H * 4, stream);

  k_hist<<<nr * NCHUNK, 256, 0, stream>>>(src, dst, ppack, E);
  k_reduce<<<(N + 255) / 256, 256, 0, stream>>>(ppack, ind, onorm, inorm, N);
  k_scan_blocks<<<nb, 1024, 0, stream>>>(ind, row_ptr, blk_sums, N);
  k_scan_tops<<<1, 1024, 0, stream>>>(blk_sums, blk_offs, row_ptr, nb, N);
  k_scan_add<<<(N + 255) / 256, 256, 0, stream>>>(row_ptr, blk_offs, N);
  k_fill_nr<<<nr * NCHUNK, 256, 0, stream>>>(src, dst, row_ptr, ppack, csr, N, E);

  int gblk = (N + 31) / 32;
  // embedding_in: hb0 = bf16(silu(x @ W_in + b_in) * onorm)
  k_gemm<<<gblk, 256, 0, stream>>>(x, W_in, b_in, onorm, nullptr, hb, N, K_IN, 1);

  // layer 0
  k_gather_bf<<<N, 64, 0, stream>>>((const unsigned*)hb, csr, row_ptr, inorm, agg, N);
  k_gemm<<<gblk, 256, 0, stream>>>(agg, W_g0, b_g0, onorm, nullptr, hb, N, H, 1);
  // layer 1
  k_gather_bf<<<N, 64, 0, stream>>>((const unsigned*)hb, csr, row_ptr, inorm, agg, N);
  k_gemm<<<gblk, 256, 0, stream>>>(agg, W_g1, b_g1, onorm, nullptr, hb, N, H, 1);
  // layer 2: output feeds GEMM (sequential) -> fp32 in place
  k_gather_bf<<<N, 64, 0, stream>>>((const unsigned*)hb, csr, row_ptr, inorm, agg, N);
  k_gemm<<<gblk, 256, 0, stream>>>(agg, W_g2, b_g2, nullptr, agg, nullptr, N, H, 1);

  // embedding_out (no act), in-place
  k_gemm<<<gblk, 256, 0, stream>>>(agg, W_out, b_out, nullptr, agg, nullptr, N, H, 0);

  k_pool<<<(N + 127) / 128, 128, 0, stream>>>(agg, gid, pooled, N);
  k_ff<<<G, 128, 0, stream>>>(pooled, W_ff, b_ff, out, G);
}